// Round 2
// baseline (627.862 us; speedup 1.0000x reference)
//
#include <hip/hip_runtime.h>
#include <hip/hip_bf16.h>
#include <math.h>

#define CC   128          // channels
#define HWN  16384        // H*W
#define EE   4            // experts
#define RR   64           // rank
#define TP   64           // pixels per tile in k_experts
#define NT   (HWN / TP)   // 256 tiles per batch image

// ---------- helpers ----------
__device__ __forceinline__ float bf2f_lo(unsigned int u) { return __uint_as_float(u << 16); }
__device__ __forceinline__ float bf2f_hi(unsigned int u) { return __uint_as_float(u & 0xffff0000u); }

__device__ __forceinline__ unsigned short f2bf(float f) {
    __hip_bfloat16 h = __float2bfloat16(f);
    return *reinterpret_cast<unsigned short*>(&h);
}
__device__ __forceinline__ unsigned int pack_bf2(float a, float b) {
    return (unsigned int)f2bf(a) | ((unsigned int)f2bf(b) << 16);
}

__device__ __forceinline__ float gelu_exact(float v) {
    return 0.5f * v * (1.0f + erff(v * 0.7071067811865475f));
}
__device__ __forceinline__ float silu_f(float v) {
    return v / (1.0f + expf(-v));
}

// acc[j] += sum_k w[k] * v_k[j]   (4 c-steps x 4 pixels)
__device__ __forceinline__ void fma4x4(float (&a)[4], float4 w,
                                       float4 v0, float4 v1, float4 v2, float4 v3) {
    a[0] += w.x*v0.x + w.y*v1.x + w.z*v2.x + w.w*v3.x;
    a[1] += w.x*v0.y + w.y*v1.y + w.z*v2.y + w.w*v3.y;
    a[2] += w.x*v0.z + w.y*v1.z + w.z*v2.z + w.w*v3.z;
    a[3] += w.x*v0.w + w.y*v1.w + w.z*v2.w + w.w*v3.w;
}

// ---------- phase 0: fold proj into exp_w2: W2p[e][d][r] = sum_c proj[d][c]*W2[e][c][r]
__global__ __launch_bounds__(256) void k_fold(
    const float* __restrict__ proj, const float* __restrict__ w2,
    float* __restrict__ w2p)
{
    const int e = blockIdx.x;
    const int tid = threadIdx.x;
    for (int idx = tid; idx < CC * RR; idx += 256) {
        const int d = idx >> 6, r = idx & 63;
        float acc = 0.f;
        for (int c = 0; c < CC; ++c)
            acc += proj[d * CC + c] * w2[(e * CC + c) * RR + r];
        w2p[(e * CC + d) * RR + r] = acc;
    }
}

// ---------- phase 1: depthwise 3x3 high-pass -> GELU -> mean; plus plain mean ----------
__device__ __forceinline__ void load_row(const float* __restrict__ pl,
                                         int row, int col0, float* d) {
    if (row < 0 || row > 127) {
        #pragma unroll
        for (int i = 0; i < 10; ++i) d[i] = 0.f;
        return;
    }
    const float4 v0 = *(const float4*)(pl + row * 128 + col0);
    const float4 v1 = *(const float4*)(pl + row * 128 + col0 + 4);
    d[1] = v0.x; d[2] = v0.y; d[3] = v0.z; d[4] = v0.w;
    d[5] = v1.x; d[6] = v1.y; d[7] = v1.z; d[8] = v1.w;
    d[0] = (col0 > 0)       ? pl[row * 128 + col0 - 1] : 0.f;
    d[9] = (col0 + 8 < 128) ? pl[row * 128 + col0 + 8] : 0.f;
}

__global__ __launch_bounds__(256) void k_convpool(
    const float* __restrict__ x,
    float* __restrict__ fe0, float* __restrict__ pooled)
{
    const int bc = blockIdx.x;               // b*C + c
    const float* pl = x + (size_t)bc * HWN;
    const int tid = threadIdx.x;
    float sg = 0.f, sx = 0.f;
    for (int g = tid; g < 2048; g += 256) {  // 8-pixel groups
        const int row  = g >> 4;
        const int col0 = (g & 15) << 3;
        float t[10], m[10], bo[10];
        load_row(pl, row - 1, col0, t);
        load_row(pl, row,     col0, m);
        load_row(pl, row + 1, col0, bo);
        #pragma unroll
        for (int j = 1; j <= 8; ++j) {
            float nb = t[j-1] + t[j] + t[j+1]
                     + m[j-1]         + m[j+1]
                     + bo[j-1] + bo[j] + bo[j+1];
            float hp = 8.f * m[j] - nb;      // zero padding at borders
            sg += gelu_exact(hp);
            sx += m[j];
        }
    }
    __shared__ float red[512];
    red[tid] = sg; red[256 + tid] = sx;
    __syncthreads();
    for (int s = 128; s > 0; s >>= 1) {
        if (tid < s) { red[tid] += red[tid + s]; red[256 + tid] += red[256 + tid + s]; }
        __syncthreads();
    }
    if (tid == 0) {
        fe0[bc]    = red[0]   * (1.f / 16384.f);
        pooled[bc] = red[256] * (1.f / 16384.f);
    }
}

// ---------- phase 2: MLP + softmax + top-2 routing (one block per batch) ----------
__global__ __launch_bounds__(256) void k_route(
    const float* __restrict__ fe0, const float* __restrict__ pooled,
    const float* __restrict__ w1, const float* __restrict__ b1,
    const float* __restrict__ w2, const float* __restrict__ b2,
    const float* __restrict__ gw, const float* __restrict__ fgw,
    float* __restrict__ gates, float* __restrict__ gsum)
{
    const int b = blockIdx.x;
    const int tid = threadIdx.x;
    __shared__ float hh[256];
    __shared__ float fe[128];
    __shared__ float lg[4];
    float acc = b1[tid];
    for (int c = 0; c < CC; ++c)
        acc += fe0[b * CC + c] * w1[c * 256 + tid];
    hh[tid] = gelu_exact(acc);
    __syncthreads();
    if (tid < 128) {
        float a2 = b2[tid];
        for (int j = 0; j < 256; ++j)
            a2 += hh[j] * w2[j * 128 + tid];
        fe[tid] = a2;
    }
    __syncthreads();
    if (tid < EE) {
        float l = 0.f;
        for (int c = 0; c < CC; ++c)
            l += pooled[b * CC + c] * gw[c * EE + tid]
               + fe[c]              * fgw[c * EE + tid];
        lg[tid] = l;
    }
    __syncthreads();
    if (tid == 0) {
        float mx = fmaxf(fmaxf(lg[0], lg[1]), fmaxf(lg[2], lg[3]));
        float sc[EE]; float ssum = 0.f;
        for (int e = 0; e < EE; ++e) { sc[e] = expf(lg[e] - mx); ssum += sc[e]; }
        float inv = 1.f / ssum;
        for (int e = 0; e < EE; ++e) sc[e] *= inv;
        int i1 = 0;
        for (int e = 1; e < EE; ++e) if (sc[e] > sc[i1]) i1 = e;   // ties: keep lowest idx
        int i2 = -1;
        for (int e = 0; e < EE; ++e) {
            if (e == i1) continue;
            if (i2 < 0 || sc[e] > sc[i2]) i2 = e;
        }
        for (int e = 0; e < EE; ++e)
            gates[b * EE + e] = (e == i1) ? sc[i1] : (e == i2 ? sc[i2] : 0.f);
        gsum[b] = sc[i1] + sc[i2];
    }
}

// ---------- phase 3: experts + gated combine + proj (fused, per 64-pixel tile) ----------
__global__ __launch_bounds__(256) void k_experts(
    const float* __restrict__ x,
    const float* __restrict__ sh,
    const float* __restrict__ w0f,
    const float* __restrict__ w1f,
    const float* __restrict__ w2p,
    const float* __restrict__ projf,
    const float* __restrict__ gates,
    const float* __restrict__ gsum,
    float* __restrict__ out)
{
    __shared__ float        xs[CC * TP];        // 32 KB fp32 x tile
    __shared__ unsigned int ssh[CC * TP / 2];   // 16 KB bf16-packed shared tile
    __shared__ float        us[RR * TP];        // 16 KB fp32 expert intermediate
    const int b    = blockIdx.x >> 8;
    const int tile = blockIdx.x & (NT - 1);
    const int p0   = tile * TP;
    const int tid  = threadIdx.x;

    // ---- stage x (fp32) and shared (packed to bf16) ----
    {
        const float4* xg = (const float4*)(x  + (size_t)b * CC * HWN + p0);
        float4* xsw = (float4*)xs;
        for (int li = tid; li < CC * TP / 4; li += 256) {   // 2048 float4 (4 px each)
            int c = li >> 4, q = li & 15;
            xsw[li] = xg[c * (HWN / 4) + q];
        }
        const float4* sg = (const float4*)(sh + (size_t)b * CC * HWN + p0);
        uint4* sl = (uint4*)ssh;
        for (int li = tid; li < CC * TP / 8; li += 256) {   // 1024 chunks of 8 px
            int c = li >> 3, q8 = li & 7;
            float4 f0 = sg[c * (HWN / 4) + q8 * 2];
            float4 f1 = sg[c * (HWN / 4) + q8 * 2 + 1];
            sl[li] = make_uint4(pack_bf2(f0.x, f0.y), pack_bf2(f0.z, f0.w),
                                pack_bf2(f1.x, f1.y), pack_bf2(f1.z, f1.w));
        }
    }
    __syncthreads();

    const int pg = tid & 15;                      // pixel quad (4 px)
    const float4* xs4 = (const float4*)xs;
    const float4* us4 = (const float4*)us;
    const uint2*  ss2 = (const uint2*)ssh;

    // ---- gsum * (proj . x) ----
    float acc[8][4];
    #pragma unroll
    for (int i = 0; i < 8; ++i)
        #pragma unroll
        for (int j = 0; j < 4; ++j) acc[i][j] = 0.f;
    {
        const int d0 = (tid >> 4) * 8;
        for (int c = 0; c < CC; c += 4) {
            float4 xv0 = xs4[(c+0)*16 + pg];
            float4 xv1 = xs4[(c+1)*16 + pg];
            float4 xv2 = xs4[(c+2)*16 + pg];
            float4 xv3 = xs4[(c+3)*16 + pg];
            #pragma unroll
            for (int i = 0; i < 8; ++i) {
                float4 pv = *(const float4*)(projf + (d0 + i) * CC + c);
                fma4x4(acc[i], pv, xv0, xv1, xv2, xv3);
            }
        }
        const float gs = gsum[b];
        #pragma unroll
        for (int i = 0; i < 8; ++i)
            #pragma unroll
            for (int j = 0; j < 4; ++j) acc[i][j] *= gs;
    }

    // ---- active experts ----
    for (int e = 0; e < EE; ++e) {
        const float ge = gates[b * EE + e];
        if (ge == 0.f) continue;                  // uniform across block
        __syncthreads();                          // us free for overwrite
        {   // u[r][p] = ge * (W0.x) * silu(W1.shared)
            const int r0 = (tid >> 4) * 4;
            const float* w0e = w0f + (e * RR + r0) * CC;
            const float* w1e = w1f + (e * RR + r0) * CC;
            float aa[4][4], gg[4][4];
            #pragma unroll
            for (int i = 0; i < 4; ++i)
                #pragma unroll
                for (int j = 0; j < 4; ++j) { aa[i][j] = 0.f; gg[i][j] = 0.f; }
            for (int c = 0; c < CC; c += 4) {
                float4 xv0 = xs4[(c+0)*16 + pg];
                float4 xv1 = xs4[(c+1)*16 + pg];
                float4 xv2 = xs4[(c+2)*16 + pg];
                float4 xv3 = xs4[(c+3)*16 + pg];
                uint2 u0 = ss2[(c+0)*16 + pg];
                uint2 u1 = ss2[(c+1)*16 + pg];
                uint2 u2 = ss2[(c+2)*16 + pg];
                uint2 u3 = ss2[(c+3)*16 + pg];
                float4 sv0 = make_float4(bf2f_lo(u0.x), bf2f_hi(u0.x), bf2f_lo(u0.y), bf2f_hi(u0.y));
                float4 sv1 = make_float4(bf2f_lo(u1.x), bf2f_hi(u1.x), bf2f_lo(u1.y), bf2f_hi(u1.y));
                float4 sv2 = make_float4(bf2f_lo(u2.x), bf2f_hi(u2.x), bf2f_lo(u2.y), bf2f_hi(u2.y));
                float4 sv3 = make_float4(bf2f_lo(u3.x), bf2f_hi(u3.x), bf2f_lo(u3.y), bf2f_hi(u3.y));
                #pragma unroll
                for (int i = 0; i < 4; ++i) {
                    float4 w0v = *(const float4*)(w0e + i * CC + c);
                    float4 w1v = *(const float4*)(w1e + i * CC + c);
                    fma4x4(aa[i], w0v, xv0, xv1, xv2, xv3);
                    fma4x4(gg[i], w1v, sv0, sv1, sv2, sv3);
                }
            }
            float4* usw = (float4*)us;
            #pragma unroll
            for (int i = 0; i < 4; ++i) {
                float4 uv;
                uv.x = ge * aa[i][0] * silu_f(gg[i][0]);
                uv.y = ge * aa[i][1] * silu_f(gg[i][1]);
                uv.z = ge * aa[i][2] * silu_f(gg[i][2]);
                uv.w = ge * aa[i][3] * silu_f(gg[i][3]);
                usw[(r0 + i) * 16 + pg] = uv;
            }
        }
        __syncthreads();                          // us visible
        {   // acc += W2p_e . u
            const int d0 = (tid >> 4) * 8;
            const float* w2e = w2p + (e * CC + d0) * RR;
            for (int r = 0; r < RR; r += 4) {
                float4 uv0 = us4[(r+0)*16 + pg];
                float4 uv1 = us4[(r+1)*16 + pg];
                float4 uv2 = us4[(r+2)*16 + pg];
                float4 uv3 = us4[(r+3)*16 + pg];
                #pragma unroll
                for (int i = 0; i < 8; ++i) {
                    float4 wv = *(const float4*)(w2e + i * RR + r);
                    fma4x4(acc[i], wv, uv0, uv1, uv2, uv3);
                }
            }
        }
    }

    // ---- store fp32 ----
    {
        const int d0 = (tid >> 4) * 8;
        float* ob = out + (size_t)(b * CC + d0) * HWN + p0 + pg * 4;
        #pragma unroll
        for (int i = 0; i < 8; ++i) {
            float4 ov = make_float4(acc[i][0], acc[i][1], acc[i][2], acc[i][3]);
            *(float4*)(ob + (size_t)i * HWN) = ov;
        }
    }
}

// ---------- launch ----------
extern "C" void kernel_launch(void* const* d_in, const int* in_sizes, int n_in,
                              void* d_out, int out_size, void* d_ws, size_t ws_size,
                              hipStream_t stream) {
    const float* x    = (const float*)d_in[0];
    const float* shr  = (const float*)d_in[1];
    const float* mw1  = (const float*)d_in[2];
    const float* mb1  = (const float*)d_in[3];
    const float* mw2  = (const float*)d_in[4];
    const float* mb2  = (const float*)d_in[5];
    const float* gw   = (const float*)d_in[6];
    const float* fgw  = (const float*)d_in[7];
    const float* ew0  = (const float*)d_in[8];
    const float* ew1  = (const float*)d_in[9];
    const float* ew2  = (const float*)d_in[10];
    const float* pw   = (const float*)d_in[11];
    float* out = (float*)d_out;

    float* ws     = (float*)d_ws;
    float* fe0    = ws + 0;        // 1024
    float* pooled = ws + 1024;     // 1024
    float* gates  = ws + 2048;     // 32
    float* gsum   = ws + 2080;     // 8 (+pad to 16B)
    float* w2p    = ws + 2112;     // 32768  -> total ~136 KB

    k_fold    <<<EE,      256, 0, stream>>>(pw, ew2, w2p);
    k_convpool<<<8 * CC,  256, 0, stream>>>(x, fe0, pooled);
    k_route   <<<8,       256, 0, stream>>>(fe0, pooled, mw1, mb1, mw2, mb2, gw, fgw, gates, gsum);
    k_experts <<<8 * NT,  256, 0, stream>>>(x, shr, ew0, ew1, w2p, pw, gates, gsum, out);
}

// Round 3
// 278.272 us; speedup vs baseline: 2.2563x; 2.2563x over previous
//
#include <hip/hip_runtime.h>
#include <hip/hip_bf16.h>
#include <math.h>

#define CC   128          // channels
#define HWN  16384        // H*W
#define EE   4            // experts
#define RR   64           // rank
#define TP   64           // pixels per tile in k_experts
#define NT   (HWN / TP)   // 256 tiles per batch image

#define XS_STRIDE 136     // shorts per pixel row in xs/shs (128 + 8 pad; 272B, 16B-aligned)
#define US_STRIDE 72      // shorts per pixel row in us (64 + 8 pad; 144B, 16B-aligned)

typedef __attribute__((ext_vector_type(8))) short short8;
typedef __attribute__((ext_vector_type(4))) float f32x4;

// ---------- helpers ----------
__device__ __forceinline__ unsigned short f2bf(float f) {
    __hip_bfloat16 h = __float2bfloat16(f);
    return *reinterpret_cast<unsigned short*>(&h);
}
__device__ __forceinline__ float gelu_exact(float v) {
    return 0.5f * v * (1.0f + erff(v * 0.7071067811865475f));
}
__device__ __forceinline__ float silu_f(float v) {
    return v / (1.0f + expf(-v));
}

// ---------- phase 0: weight prep ----------
// blocks 0..127 : convert proj/w0/w1 -> bf16 (32768 threads)
// blocks 128..255 : w2p[e][d][r] = sum_c proj[d][c]*w2[e][c][r]  -> bf16
__global__ __launch_bounds__(256) void k_weights(
    const float* __restrict__ proj, const float* __restrict__ w0,
    const float* __restrict__ w1,   const float* __restrict__ w2,
    unsigned short* __restrict__ projb, unsigned short* __restrict__ w0b,
    unsigned short* __restrict__ w1b,   unsigned short* __restrict__ w2pb)
{
    const int bx = blockIdx.x, tid = threadIdx.x;
    if (bx < 128) {
        int i = bx * 256 + tid;                     // 0..32767
        if (i < CC * CC) projb[i] = f2bf(proj[i]);
        w0b[i] = f2bf(w0[i]);
        w1b[i] = f2bf(w1[i]);
    } else {
        const int bb = bx - 128;                    // 0..127
        const int e  = bb >> 5;                     // 0..3
        const int d  = ((bb & 31) << 2) + (tid >> 6);
        const int r  = tid & 63;
        const float* pr = proj + d * CC;
        const float* wz = w2 + (size_t)e * CC * RR + r;
        float a0 = 0.f, a1 = 0.f, a2 = 0.f, a3 = 0.f;
        for (int c = 0; c < CC; c += 4) {
            a0 += pr[c+0] * wz[(c+0) * RR];
            a1 += pr[c+1] * wz[(c+1) * RR];
            a2 += pr[c+2] * wz[(c+2) * RR];
            a3 += pr[c+3] * wz[(c+3) * RR];
        }
        w2pb[(e * CC + d) * RR + r] = f2bf((a0 + a1) + (a2 + a3));
    }
}

// ---------- phase 1: depthwise 3x3 high-pass -> GELU -> mean; plus plain mean ----------
#define IMS 129   // padded row stride (floats): bank = (r + c) % 32 -> conflict-free reads
__global__ __launch_bounds__(256) void k_convpool(
    const float* __restrict__ x,
    float* __restrict__ fe0, float* __restrict__ pooled)
{
    __shared__ float img[128 * IMS];   // ~66 KB
    __shared__ float wred[8];
    const int bc = blockIdx.x, tid = threadIdx.x;
    const float4* g = (const float4*)(x + (size_t)bc * HWN);
    for (int i = tid; i < HWN / 4; i += 256) {          // coalesced read, scalar LDS writes
        const int r = i >> 5, cq = (i & 31) << 2;
        float4 v = g[i];
        float* d = img + r * IMS + cq;
        d[0] = v.x; d[1] = v.y; d[2] = v.z; d[3] = v.w;
    }
    __syncthreads();
    const int r  = tid >> 1;
    const int c0 = (tid & 1) << 6;
    const float* rm = img + r * IMS + c0;
    const bool has_t = (r > 0), has_b = (r < 127);
    float sg = 0.f, sx = 0.f;
    for (int j = 0; j < 64; ++j) {
        const int cc = c0 + j;
        const float m  = rm[j];
        float s = ((cc > 0) ? rm[j-1] : 0.f) + ((cc < 127) ? rm[j+1] : 0.f);
        if (has_t) {
            const float* rw = rm - IMS;
            s += rw[j] + ((cc > 0) ? rw[j-1] : 0.f) + ((cc < 127) ? rw[j+1] : 0.f);
        }
        if (has_b) {
            const float* rw = rm + IMS;
            s += rw[j] + ((cc > 0) ? rw[j-1] : 0.f) + ((cc < 127) ? rw[j+1] : 0.f);
        }
        sg += gelu_exact(8.f * m - s);
        sx += m;
    }
    for (int off = 32; off > 0; off >>= 1) {
        sg += __shfl_down(sg, off, 64);
        sx += __shfl_down(sx, off, 64);
    }
    if ((tid & 63) == 0) { wred[tid >> 6] = sg; wred[4 + (tid >> 6)] = sx; }
    __syncthreads();
    if (tid == 0) {
        fe0[bc]    = (wred[0] + wred[1] + wred[2] + wred[3]) * (1.f / 16384.f);
        pooled[bc] = (wred[4] + wred[5] + wred[6] + wred[7]) * (1.f / 16384.f);
    }
}

// ---------- phase 2: MLP + softmax + top-2 routing (one block per batch) ----------
__global__ __launch_bounds__(256) void k_route(
    const float* __restrict__ fe0, const float* __restrict__ pooled,
    const float* __restrict__ w1, const float* __restrict__ b1,
    const float* __restrict__ w2, const float* __restrict__ b2,
    const float* __restrict__ gw, const float* __restrict__ fgw,
    float* __restrict__ gates, float* __restrict__ gsum)
{
    const int b = blockIdx.x, tid = threadIdx.x;
    __shared__ float hh[256];
    __shared__ float fe[128];
    __shared__ float lg[4];
    {
        const float* f0 = fe0 + b * CC;
        float a[8];
        #pragma unroll
        for (int j = 0; j < 8; ++j) a[j] = 0.f;
        for (int c = 0; c < CC; c += 8)
            #pragma unroll
            for (int j = 0; j < 8; ++j) a[j] += f0[c + j] * w1[(c + j) * 256 + tid];
        float acc = b1[tid] + ((a[0]+a[1]) + (a[2]+a[3])) + ((a[4]+a[5]) + (a[6]+a[7]));
        hh[tid] = gelu_exact(acc);
    }
    __syncthreads();
    if (tid < 128) {
        float a[8];
        #pragma unroll
        for (int j = 0; j < 8; ++j) a[j] = 0.f;
        for (int c = 0; c < 256; c += 8)
            #pragma unroll
            for (int j = 0; j < 8; ++j) a[j] += hh[c + j] * w2[(c + j) * 128 + tid];
        fe[tid] = b2[tid] + ((a[0]+a[1]) + (a[2]+a[3])) + ((a[4]+a[5]) + (a[6]+a[7]));
    }
    __syncthreads();
    if (tid < EE) {
        const float* pl = pooled + b * CC;
        float l0=0.f, l1=0.f, l2=0.f, l3=0.f;
        for (int c = 0; c < CC; c += 4) {
            l0 += pl[c+0] * gw[(c+0) * EE + tid] + fe[c+0] * fgw[(c+0) * EE + tid];
            l1 += pl[c+1] * gw[(c+1) * EE + tid] + fe[c+1] * fgw[(c+1) * EE + tid];
            l2 += pl[c+2] * gw[(c+2) * EE + tid] + fe[c+2] * fgw[(c+2) * EE + tid];
            l3 += pl[c+3] * gw[(c+3) * EE + tid] + fe[c+3] * fgw[(c+3) * EE + tid];
        }
        lg[tid] = (l0 + l1) + (l2 + l3);
    }
    __syncthreads();
    if (tid == 0) {
        float mx = fmaxf(fmaxf(lg[0], lg[1]), fmaxf(lg[2], lg[3]));
        float sc[EE]; float ssum = 0.f;
        for (int e = 0; e < EE; ++e) { sc[e] = expf(lg[e] - mx); ssum += sc[e]; }
        float inv = 1.f / ssum;
        for (int e = 0; e < EE; ++e) sc[e] *= inv;
        int i1 = 0;
        for (int e = 1; e < EE; ++e) if (sc[e] > sc[i1]) i1 = e;
        int i2 = -1;
        for (int e = 0; e < EE; ++e) {
            if (e == i1) continue;
            if (i2 < 0 || sc[e] > sc[i2]) i2 = e;
        }
        for (int e = 0; e < EE; ++e)
            gates[b * EE + e] = (e == i1) ? sc[i1] : (e == i2 ? sc[i2] : 0.f);
        gsum[b] = sc[i1] + sc[i2];
    }
}

// ---------- phase 3: experts + combine + proj, MFMA bf16 (per 64-pixel tile) ----------
__global__ __launch_bounds__(256, 3) void k_experts(
    const float* __restrict__ x, const float* __restrict__ sh,
    const unsigned short* __restrict__ w0b, const unsigned short* __restrict__ w1b,
    const unsigned short* __restrict__ w2pb, const unsigned short* __restrict__ projb,
    const float* __restrict__ gates, const float* __restrict__ gsum,
    float* __restrict__ out)
{
    __shared__ __align__(16) unsigned short xs [TP * XS_STRIDE];  // 17408 B
    __shared__ __align__(16) unsigned short shs[TP * XS_STRIDE];  // 17408 B
    __shared__ __align__(16) unsigned short us [TP * US_STRIDE];  //  9216 B
    const int tid  = threadIdx.x;
    const int b    = blockIdx.x >> 8;
    const int tile = blockIdx.x & (NT - 1);
    const int p0   = tile * TP;

    // ---- stage x/sh: column-wise coalesced global reads -> k-major bf16 LDS ----
    {
        const int p  = tid & 63;
        const int cb = tid >> 6;                    // 0..3
        const float* xp = x  + (size_t)b * CC * HWN + p0 + p;
        const float* sp = sh + (size_t)b * CC * HWN + p0 + p;
        for (int it = 0; it < 4; ++it) {
            const int c0 = it * 32 + cb * 8;
            unsigned short t0[8], t1[8];
            #pragma unroll
            for (int j = 0; j < 8; ++j) t0[j] = f2bf(xp[(size_t)(c0 + j) * HWN]);
            #pragma unroll
            for (int j = 0; j < 8; ++j) t1[j] = f2bf(sp[(size_t)(c0 + j) * HWN]);
            *(uint4*)&xs [p * XS_STRIDE + c0] = *(uint4*)t0;
            *(uint4*)&shs[p * XS_STRIDE + c0] = *(uint4*)t1;
        }
    }
    __syncthreads();

    const int wv = tid >> 6;        // wave 0..3
    const int ln = tid & 63;
    const int lp = ln & 15;         // m/n index within 16-tile
    const int lq = ln >> 4;         // quad: k-offset/8 (A,B), row-offset/4 (C/D)

    f32x4 acc[2][4];                // [d-tile][p-tile], d in [wv*32, wv*32+32)
    #pragma unroll
    for (int i = 0; i < 2; ++i)
        #pragma unroll
        for (int j = 0; j < 4; ++j) acc[i][j] = (f32x4){0.f, 0.f, 0.f, 0.f};

    // ---- proj stage: acc = proj @ x  (K=128) ----
    {
        const int d0 = wv * 32;
        #pragma unroll
        for (int ks = 0; ks < 4; ++ks) {
            const int k0 = ks * 32 + lq * 8;
            short8 a0 = *(const short8*)&projb[(d0 +      lp) * CC + k0];
            short8 a1 = *(const short8*)&projb[(d0 + 16 + lp) * CC + k0];
            #pragma unroll
            for (int pt = 0; pt < 4; ++pt) {
                short8 bf = *(const short8*)&xs[(pt * 16 + lp) * XS_STRIDE + k0];
                acc[0][pt] = __builtin_amdgcn_mfma_f32_16x16x32_bf16(a0, bf, acc[0][pt], 0, 0, 0);
                acc[1][pt] = __builtin_amdgcn_mfma_f32_16x16x32_bf16(a1, bf, acc[1][pt], 0, 0, 0);
            }
        }
        const float gs = gsum[b];
        #pragma unroll
        for (int i = 0; i < 2; ++i)
            #pragma unroll
            for (int j = 0; j < 4; ++j) acc[i][j] *= gs;
    }

    // ---- experts ----
    for (int e = 0; e < EE; ++e) {
        const float ge = gates[b * EE + e];
        if (ge == 0.f) continue;                       // block-uniform

        // stage A: a = W0 @ x, g = W1 @ sh   rows r in [wv*16, wv*16+16), K=128
        f32x4 af[4], gf[4];
        #pragma unroll
        for (int pt = 0; pt < 4; ++pt) { af[pt] = (f32x4){0.f,0.f,0.f,0.f}; gf[pt] = (f32x4){0.f,0.f,0.f,0.f}; }
        const unsigned short* w0e = w0b + (size_t)(e * RR + wv * 16) * CC;
        const unsigned short* w1e = w1b + (size_t)(e * RR + wv * 16) * CC;
        #pragma unroll
        for (int ks = 0; ks < 4; ++ks) {
            const int k0 = ks * 32 + lq * 8;
            short8 a0 = *(const short8*)&w0e[lp * CC + k0];
            short8 a1 = *(const short8*)&w1e[lp * CC + k0];
            #pragma unroll
            for (int pt = 0; pt < 4; ++pt) {
                short8 bx = *(const short8*)&xs [(pt * 16 + lp) * XS_STRIDE + k0];
                short8 bs = *(const short8*)&shs[(pt * 16 + lp) * XS_STRIDE + k0];
                af[pt] = __builtin_amdgcn_mfma_f32_16x16x32_bf16(a0, bx, af[pt], 0, 0, 0);
                gf[pt] = __builtin_amdgcn_mfma_f32_16x16x32_bf16(a1, bs, gf[pt], 0, 0, 0);
            }
        }
        __syncthreads();   // prev expert's us fully consumed
        // u = ge * a * silu(g) -> bf16 -> us[p][r]  (C layout: row r = wv*16+lq*4+i, col p)
        #pragma unroll
        for (int pt = 0; pt < 4; ++pt) {
            unsigned short t[4];
            #pragma unroll
            for (int i = 0; i < 4; ++i)
                t[i] = f2bf(ge * af[pt][i] * silu_f(gf[pt][i]));
            *(uint2*)&us[(pt * 16 + lp) * US_STRIDE + wv * 16 + lq * 4] = *(uint2*)t;
        }
        __syncthreads();   // us visible to all waves
        // stage B: acc += W2p[e] @ u   (K=64)
        const unsigned short* w2e = w2pb + (size_t)(e * CC + wv * 32) * RR;
        #pragma unroll
        for (int ks = 0; ks < 2; ++ks) {
            const int k0 = ks * 32 + lq * 8;
            short8 a0 = *(const short8*)&w2e[lp * RR + k0];
            short8 a1 = *(const short8*)&w2e[(16 + lp) * RR + k0];
            #pragma unroll
            for (int pt = 0; pt < 4; ++pt) {
                short8 bu = *(const short8*)&us[(pt * 16 + lp) * US_STRIDE + k0];
                acc[0][pt] = __builtin_amdgcn_mfma_f32_16x16x32_bf16(a0, bu, acc[0][pt], 0, 0, 0);
                acc[1][pt] = __builtin_amdgcn_mfma_f32_16x16x32_bf16(a1, bu, acc[1][pt], 0, 0, 0);
            }
        }
    }

    // ---- store: lane holds (d = wv*32 + dt*16 + lq*4 + i, p = p0 + pt*16 + lp) ----
    {
        const int d0 = wv * 32;
        #pragma unroll
        for (int dt = 0; dt < 2; ++dt)
            #pragma unroll
            for (int pt = 0; pt < 4; ++pt) {
                float* ob = out + ((size_t)(b * CC + d0 + dt * 16 + lq * 4)) * HWN + p0 + pt * 16 + lp;
                #pragma unroll
                for (int i = 0; i < 4; ++i)
                    ob[(size_t)i * HWN] = acc[dt][pt][i];
            }
    }
}

// ---------- launch ----------
extern "C" void kernel_launch(void* const* d_in, const int* in_sizes, int n_in,
                              void* d_out, int out_size, void* d_ws, size_t ws_size,
                              hipStream_t stream) {
    const float* x    = (const float*)d_in[0];
    const float* shr  = (const float*)d_in[1];
    const float* mw1  = (const float*)d_in[2];
    const float* mb1  = (const float*)d_in[3];
    const float* mw2  = (const float*)d_in[4];
    const float* mb2  = (const float*)d_in[5];
    const float* gw   = (const float*)d_in[6];
    const float* fgw  = (const float*)d_in[7];
    const float* ew0  = (const float*)d_in[8];
    const float* ew1  = (const float*)d_in[9];
    const float* ew2  = (const float*)d_in[10];
    const float* pw   = (const float*)d_in[11];
    float* out = (float*)d_out;

    float* ws     = (float*)d_ws;
    float* fe0    = ws + 0;        // 1024 f
    float* pooled = ws + 1024;     // 1024 f
    float* gates  = ws + 2048;     // 32 f
    float* gsum   = ws + 2080;     // 8 f (+pad)
    unsigned short* projb = (unsigned short*)(ws + 2112);   // 16384 us
    unsigned short* w0b   = projb + 16384;                  // 32768 us
    unsigned short* w1b   = w0b + 32768;                    // 32768 us
    unsigned short* w2pb  = w1b + 32768;                    // 32768 us  (~237 KB total)

    k_weights <<<256,     256, 0, stream>>>(pw, ew0, ew1, ew2, projb, w0b, w1b, w2pb);
    k_convpool<<<8 * CC,  256, 0, stream>>>(x, fe0, pooled);
    k_route   <<<8,       256, 0, stream>>>(fe0, pooled, mw1, mb1, mw2, mb2, gw, fgw, gates, gsum);
    k_experts <<<8 * NT,  256, 0, stream>>>(x, shr, w0b, w1b, w2pb, projb, gates, gsum, out);
}

// Round 4
// 259.754 us; speedup vs baseline: 2.4171x; 1.0713x over previous
//
#include <hip/hip_runtime.h>
#include <hip/hip_bf16.h>
#include <math.h>

#define CC   128          // channels
#define HWN  16384        // H*W
#define EE   4            // experts
#define RR   64           // rank
#define TP   64           // pixels per tile in k_experts
#define NT   (HWN / TP)   // 256 tiles per batch image

typedef __attribute__((ext_vector_type(8))) short short8;
typedef __attribute__((ext_vector_type(4))) float f32x4;

// ---------- helpers ----------
__device__ __forceinline__ unsigned short f2bf(float f) {
    __hip_bfloat16 h = __float2bfloat16(f);
    return *reinterpret_cast<unsigned short*>(&h);
}
__device__ __forceinline__ float gelu_exact(float v) {
    return 0.5f * v * (1.0f + erff(v * 0.7071067811865475f));
}
__device__ __forceinline__ float silu_f(float v) {
    return v / (1.0f + expf(-v));
}

// ======================================================================
// k_prep: fused  (a) depthwise-3x3-highpass -> gelu -> mean + plain mean
//                (b) weight bf16 conversion + proj-fold into W2
//                (c) L3 warm of sh / MLP weights (cold-miss removal)
// ======================================================================
#define IMS 129                    // padded row stride: bank=(r+c)%32 -> 2-way max
#define PREP_CONV 1024
#define PREP_WCV  (PREP_CONV + 128)    // 128 convert blocks
#define PREP_WF   (PREP_WCV + 128)     // 128 fold blocks
#define PREP_SHW  (PREP_WF + 512)      // 512 sh-warm blocks
#define PREP_MLW  (PREP_SHW + 48)      // 48 mlp-warm blocks
__global__ __launch_bounds__(256) void k_prep(
    const float* __restrict__ x,   const float* __restrict__ sh,
    const float* __restrict__ proj,
    const float* __restrict__ ew0, const float* __restrict__ ew1,
    const float* __restrict__ ew2,
    const float* __restrict__ mw1, const float* __restrict__ mw2,
    const float* __restrict__ gw,  const float* __restrict__ fgw,
    float* __restrict__ fe0, float* __restrict__ pooled,
    unsigned short* __restrict__ projb, unsigned short* __restrict__ w0b,
    unsigned short* __restrict__ w1b,   unsigned short* __restrict__ w2pb,
    float* __restrict__ dummy)
{
    __shared__ float img[129 * IMS];   // rows 0..127 data, row 128 = zeros
    __shared__ float wred[8];
    const int bx = blockIdx.x, tid = threadIdx.x;

    if (bx < PREP_CONV) {
        // ---- conv + pool for image bc ----
        const int bc = bx;
        const float4* g = (const float4*)(x + (size_t)bc * HWN);
        for (int i = tid; i < HWN / 4; i += 256) {
            const int r = i >> 5, cq = (i & 31) << 2;
            float4 v = g[i];
            float* d = img + r * IMS + cq;
            d[0] = v.x; d[1] = v.y; d[2] = v.z; d[3] = v.w;
        }
        for (int i = tid; i < IMS; i += 256) img[128 * IMS + i] = 0.f;  // zero row
        __syncthreads();

        const int r  = tid >> 1;
        const int c0 = (tid & 1) << 6;
        const float* pm  = img + r * IMS + c0;
        const float* pt_ = img + ((r > 0)   ? (r - 1) : 128) * IMS + c0;
        const float* pb_ = img + ((r < 127) ? (r + 1) : 128) * IMS + c0;
        float l0, l1, l2, m0, m1, m2;
        if (c0 == 0) { l0 = l1 = l2 = 0.f; }
        else         { l0 = pt_[-1]; l1 = pm[-1]; l2 = pb_[-1]; }
        m0 = pt_[0]; m1 = pm[0]; m2 = pb_[0];
        float sg = 0.f, sx = 0.f;
        #pragma unroll 7
        for (int j = 0; j < 63; ++j) {
            float n0 = pt_[j + 1], n1 = pm[j + 1], n2 = pb_[j + 1];
            float s8 = ((l0 + l1 + l2) + (m0 + m2)) + ((n0 + n1) + n2);
            sg += gelu_exact(8.f * m1 - s8);
            sx += m1;
            l0 = m0; l1 = m1; l2 = m2; m0 = n0; m1 = n1; m2 = n2;
        }
        {
            float n0, n1, n2;
            if (c0 == 64) { n0 = n1 = n2 = 0.f; }
            else          { n0 = pt_[64]; n1 = pm[64]; n2 = pb_[64]; }
            float s8 = ((l0 + l1 + l2) + (m0 + m2)) + ((n0 + n1) + n2);
            sg += gelu_exact(8.f * m1 - s8);
            sx += m1;
        }
        for (int off = 32; off > 0; off >>= 1) {
            sg += __shfl_down(sg, off, 64);
            sx += __shfl_down(sx, off, 64);
        }
        if ((tid & 63) == 0) { wred[tid >> 6] = sg; wred[4 + (tid >> 6)] = sx; }
        __syncthreads();
        if (tid == 0) {
            fe0[bc]    = (wred[0] + wred[1] + wred[2] + wred[3]) * (1.f / 16384.f);
            pooled[bc] = (wred[4] + wred[5] + wred[6] + wred[7]) * (1.f / 16384.f);
        }
    } else if (bx < PREP_WCV) {
        // ---- convert proj/w0/w1 to bf16 ----
        int i = (bx - PREP_CONV) * 256 + tid;      // 0..32767
        if (i < CC * CC) projb[i] = f2bf(proj[i]);
        w0b[i] = f2bf(ew0[i]);
        w1b[i] = f2bf(ew1[i]);
    } else if (bx < PREP_WF) {
        // ---- fold proj into w2 -> bf16 ----
        const int bb = bx - PREP_WCV;              // 0..127
        const int e  = bb >> 5;
        const int d  = ((bb & 31) << 2) + (tid >> 6);
        const int r  = tid & 63;
        const float* pr = proj + d * CC;
        const float* wz = ew2 + (size_t)e * CC * RR + r;
        float a0 = 0.f, a1 = 0.f, a2 = 0.f, a3 = 0.f;
        for (int c = 0; c < CC; c += 4) {
            a0 += pr[c + 0] * wz[(c + 0) * RR];
            a1 += pr[c + 1] * wz[(c + 1) * RR];
            a2 += pr[c + 2] * wz[(c + 2) * RR];
            a3 += pr[c + 3] * wz[(c + 3) * RR];
        }
        w2pb[(e * CC + d) * RR + r] = f2bf((a0 + a1) + (a2 + a3));
    } else if (bx < PREP_SHW) {
        // ---- warm sh into L3 (512 blocks x 128 KB) ----
        const int wb = bx - PREP_WF;
        const float4* s4 = (const float4*)sh + (size_t)wb * 8192;
        float s = 0.f;
        #pragma unroll 4
        for (int j = 0; j < 32; ++j) {
            float4 v = s4[j * 256 + tid];
            s += (v.x + v.y) + (v.z + v.w);
        }
        if (s == 12345.678f) dummy[0] = s;   // keep-alive, practically never taken
    } else {
        // ---- warm MLP weights + gates (48 blocks) ----
        const int i = (bx - PREP_SHW) * 256 + tid;    // 0..12287
        float s = 0.f;
        for (int j = i; j < CC * 2 * CC; j += 48 * 256) s += mw1[j] + mw2[j];
        if (i < CC * EE) s += gw[i] + fgw[i];
        if (s == 12345.678f) dummy[1] = s;
    }
}

// ---------- routing: MLP + softmax + top-2 (one block per batch) ----------
__global__ __launch_bounds__(256) void k_route(
    const float* __restrict__ fe0, const float* __restrict__ pooled,
    const float* __restrict__ w1, const float* __restrict__ b1,
    const float* __restrict__ w2, const float* __restrict__ b2,
    const float* __restrict__ gw, const float* __restrict__ fgw,
    float* __restrict__ gates, float* __restrict__ gsum)
{
    const int b = blockIdx.x, tid = threadIdx.x;
    __shared__ float hh[256];
    __shared__ float fe[128];
    __shared__ float lg[4];
    {
        const float* f0 = fe0 + b * CC;
        float a[8];
        #pragma unroll
        for (int j = 0; j < 8; ++j) a[j] = 0.f;
        for (int c = 0; c < CC; c += 8)
            #pragma unroll
            for (int j = 0; j < 8; ++j) a[j] += f0[c + j] * w1[(c + j) * 256 + tid];
        float acc = b1[tid] + ((a[0]+a[1]) + (a[2]+a[3])) + ((a[4]+a[5]) + (a[6]+a[7]));
        hh[tid] = gelu_exact(acc);
    }
    __syncthreads();
    if (tid < 128) {
        float a[8];
        #pragma unroll
        for (int j = 0; j < 8; ++j) a[j] = 0.f;
        for (int c = 0; c < 256; c += 8)
            #pragma unroll
            for (int j = 0; j < 8; ++j) a[j] += hh[c + j] * w2[(c + j) * 128 + tid];
        fe[tid] = b2[tid] + ((a[0]+a[1]) + (a[2]+a[3])) + ((a[4]+a[5]) + (a[6]+a[7]));
    }
    __syncthreads();
    if (tid < EE) {
        const float* pl = pooled + b * CC;
        float l0=0.f, l1=0.f, l2=0.f, l3=0.f;
        for (int c = 0; c < CC; c += 4) {
            l0 += pl[c+0] * gw[(c+0) * EE + tid] + fe[c+0] * fgw[(c+0) * EE + tid];
            l1 += pl[c+1] * gw[(c+1) * EE + tid] + fe[c+1] * fgw[(c+1) * EE + tid];
            l2 += pl[c+2] * gw[(c+2) * EE + tid] + fe[c+2] * fgw[(c+2) * EE + tid];
            l3 += pl[c+3] * gw[(c+3) * EE + tid] + fe[c+3] * fgw[(c+3) * EE + tid];
        }
        lg[tid] = (l0 + l1) + (l2 + l3);
    }
    __syncthreads();
    if (tid == 0) {
        float mx = fmaxf(fmaxf(lg[0], lg[1]), fmaxf(lg[2], lg[3]));
        float sc[EE]; float ssum = 0.f;
        for (int e = 0; e < EE; ++e) { sc[e] = expf(lg[e] - mx); ssum += sc[e]; }
        float inv = 1.f / ssum;
        for (int e = 0; e < EE; ++e) sc[e] *= inv;
        int i1 = 0;
        for (int e = 1; e < EE; ++e) if (sc[e] > sc[i1]) i1 = e;
        int i2 = -1;
        for (int e = 0; e < EE; ++e) {
            if (e == i1) continue;
            if (i2 < 0 || sc[e] > sc[i2]) i2 = e;
        }
        for (int e = 0; e < EE; ++e)
            gates[b * EE + e] = (e == i1) ? sc[i1] : (e == i2 ? sc[i2] : 0.f);
        gsum[b] = sc[i1] + sc[i2];
    }
}

// ======================================================================
// k_experts: experts + combine + proj, MFMA bf16, XOR-swizzled LDS
//   xs/shs: pixel p (0..63) x 16 chunks of 8 ch; chunk' = chunk ^ (p&15)
//   us    : pixel p (0..63) x  8 chunks of 8 r ; chunk' = chunk ^ (p&7)
//   -> all b128 reads/writes spread over all 32 banks; LDS = 40960 B = 4 blk/CU
// ======================================================================
__global__ __launch_bounds__(256, 4) void k_experts(
    const float* __restrict__ x, const float* __restrict__ sh,
    const unsigned short* __restrict__ w0b, const unsigned short* __restrict__ w1b,
    const unsigned short* __restrict__ w2pb, const unsigned short* __restrict__ projb,
    const float* __restrict__ gates, const float* __restrict__ gsum,
    float* __restrict__ out)
{
    __shared__ __align__(16) unsigned short xs [TP * CC];  // 16384 B
    __shared__ __align__(16) unsigned short shs[TP * CC];  // 16384 B
    __shared__ __align__(16) unsigned short us [TP * RR];  //  8192 B
    const int tid  = threadIdx.x;
    const int b    = blockIdx.x >> 8;
    const int tile = blockIdx.x & (NT - 1);
    const int p0   = tile * TP;

    // ---- stage x/sh: column-wise coalesced reads -> swizzled k-major bf16 ----
    {
        const int p  = tid & 63;
        const int cb = tid >> 6;                    // 0..3
        const float* xp = x  + (size_t)b * CC * HWN + p0 + p;
        const float* sp = sh + (size_t)b * CC * HWN + p0 + p;
        #pragma unroll
        for (int it = 0; it < 4; ++it) {
            const int c0 = it * 32 + cb * 8;
            const int sw = p * CC + (((it * 4 + cb) ^ (p & 15)) << 3);
            unsigned short t0[8], t1[8];
            #pragma unroll
            for (int j = 0; j < 8; ++j) t0[j] = f2bf(xp[(size_t)(c0 + j) * HWN]);
            #pragma unroll
            for (int j = 0; j < 8; ++j) t1[j] = f2bf(sp[(size_t)(c0 + j) * HWN]);
            *(uint4*)&xs [sw] = *(uint4*)t0;
            *(uint4*)&shs[sw] = *(uint4*)t1;
        }
    }
    __syncthreads();

    const int wv = tid >> 6;        // wave 0..3
    const int ln = tid & 63;
    const int lp = ln & 15;         // m/n index within 16-tile
    const int lq = ln >> 4;         // quad

    f32x4 acc[2][4];                // [d-tile][p-tile], d in [wv*32, wv*32+32)
    #pragma unroll
    for (int i = 0; i < 2; ++i)
        #pragma unroll
        for (int j = 0; j < 4; ++j) acc[i][j] = (f32x4){0.f, 0.f, 0.f, 0.f};

    // ---- proj stage: acc = proj @ x  (K=128) ----
    {
        const int d0 = wv * 32;
        #pragma unroll
        for (int ks = 0; ks < 4; ++ks) {
            const int k0 = ks * 32 + lq * 8;
            const int ch = ks * 4 + lq;
            short8 a0 = *(const short8*)&projb[(d0 +      lp) * CC + k0];
            short8 a1 = *(const short8*)&projb[(d0 + 16 + lp) * CC + k0];
            #pragma unroll
            for (int pt = 0; pt < 4; ++pt) {
                short8 bf = *(const short8*)&xs[(pt * 16 + lp) * CC + ((ch ^ lp) << 3)];
                acc[0][pt] = __builtin_amdgcn_mfma_f32_16x16x32_bf16(a0, bf, acc[0][pt], 0, 0, 0);
                acc[1][pt] = __builtin_amdgcn_mfma_f32_16x16x32_bf16(a1, bf, acc[1][pt], 0, 0, 0);
            }
        }
        const float gs = gsum[b];
        #pragma unroll
        for (int i = 0; i < 2; ++i)
            #pragma unroll
            for (int j = 0; j < 4; ++j) acc[i][j] *= gs;
    }

    // ---- experts ----
    for (int e = 0; e < EE; ++e) {
        const float ge = gates[b * EE + e];
        if (ge == 0.f) continue;                       // block-uniform

        // stage A: a = W0 @ x, g = W1 @ sh  (rows wv*16..wv*16+16, K=128)
        f32x4 af[4], gf[4];
        #pragma unroll
        for (int pt = 0; pt < 4; ++pt) { af[pt] = (f32x4){0.f,0.f,0.f,0.f}; gf[pt] = (f32x4){0.f,0.f,0.f,0.f}; }
        const unsigned short* w0e = w0b + (size_t)(e * RR + wv * 16) * CC;
        const unsigned short* w1e = w1b + (size_t)(e * RR + wv * 16) * CC;
        #pragma unroll
        for (int ks = 0; ks < 4; ++ks) {
            const int k0 = ks * 32 + lq * 8;
            const int ch = ks * 4 + lq;
            short8 a0 = *(const short8*)&w0e[lp * CC + k0];
            short8 a1 = *(const short8*)&w1e[lp * CC + k0];
            #pragma unroll
            for (int pt = 0; pt < 4; ++pt) {
                const int sw = (pt * 16 + lp) * CC + ((ch ^ lp) << 3);
                short8 bx = *(const short8*)&xs [sw];
                short8 bs = *(const short8*)&shs[sw];
                af[pt] = __builtin_amdgcn_mfma_f32_16x16x32_bf16(a0, bx, af[pt], 0, 0, 0);
                gf[pt] = __builtin_amdgcn_mfma_f32_16x16x32_bf16(a1, bs, gf[pt], 0, 0, 0);
            }
        }
        __syncthreads();   // prev expert's us fully consumed
        // u = ge * a * silu(g) -> bf16 -> us (C layout row r = wv*16+lq*4+i)
        #pragma unroll
        for (int pt = 0; pt < 4; ++pt) {
            unsigned short t[4];
            #pragma unroll
            for (int i = 0; i < 4; ++i)
                t[i] = f2bf(ge * af[pt][i] * silu_f(gf[pt][i]));
            const int p = pt * 16 + lp;
            const int addr = p * RR + (((wv * 2 + (lq >> 1)) ^ (lp & 7)) << 3) + ((lq & 1) << 2);
            *(uint2*)&us[addr] = *(uint2*)t;
        }
        __syncthreads();   // us visible to all waves
        // stage B: acc += W2p[e] @ u   (K=64)
        const unsigned short* w2e = w2pb + (size_t)(e * CC + wv * 32) * RR;
        #pragma unroll
        for (int ks = 0; ks < 2; ++ks) {
            const int k0 = ks * 32 + lq * 8;
            const int ch = ks * 4 + lq;
            short8 a0 = *(const short8*)&w2e[lp * RR + k0];
            short8 a1 = *(const short8*)&w2e[(16 + lp) * RR + k0];
            #pragma unroll
            for (int pt = 0; pt < 4; ++pt) {
                short8 bu = *(const short8*)&us[(pt * 16 + lp) * RR + ((ch ^ (lp & 7)) << 3)];
                acc[0][pt] = __builtin_amdgcn_mfma_f32_16x16x32_bf16(a0, bu, acc[0][pt], 0, 0, 0);
                acc[1][pt] = __builtin_amdgcn_mfma_f32_16x16x32_bf16(a1, bu, acc[1][pt], 0, 0, 0);
            }
        }
    }

    // ---- store: lane holds (d = wv*32 + dt*16 + lq*4 + i, p = p0 + pt*16 + lp) ----
    {
        const int d0 = wv * 32;
        #pragma unroll
        for (int dt = 0; dt < 2; ++dt)
            #pragma unroll
            for (int pt = 0; pt < 4; ++pt) {
                float* ob = out + ((size_t)(b * CC + d0 + dt * 16 + lq * 4)) * HWN + p0 + pt * 16 + lp;
                #pragma unroll
                for (int i = 0; i < 4; ++i)
                    ob[(size_t)i * HWN] = acc[dt][pt][i];
            }
    }
}

// ---------- launch ----------
extern "C" void kernel_launch(void* const* d_in, const int* in_sizes, int n_in,
                              void* d_out, int out_size, void* d_ws, size_t ws_size,
                              hipStream_t stream) {
    const float* x    = (const float*)d_in[0];
    const float* shr  = (const float*)d_in[1];
    const float* mw1  = (const float*)d_in[2];
    const float* mb1  = (const float*)d_in[3];
    const float* mw2  = (const float*)d_in[4];
    const float* mb2  = (const float*)d_in[5];
    const float* gw   = (const float*)d_in[6];
    const float* fgw  = (const float*)d_in[7];
    const float* ew0  = (const float*)d_in[8];
    const float* ew1  = (const float*)d_in[9];
    const float* ew2  = (const float*)d_in[10];
    const float* pw   = (const float*)d_in[11];
    float* out = (float*)d_out;

    float* ws     = (float*)d_ws;
    float* fe0    = ws + 0;        // 1024 f
    float* pooled = ws + 1024;     // 1024 f
    float* gates  = ws + 2048;     // 32 f
    float* gsum   = ws + 2080;     // 8 f
    float* dummy  = ws + 2088;     // 8 f (+pad to 2112)
    unsigned short* projb = (unsigned short*)(ws + 2112);   // 16384 us
    unsigned short* w0b   = projb + 16384;                  // 32768 us
    unsigned short* w1b   = w0b + 32768;                    // 32768 us
    unsigned short* w2pb  = w1b + 32768;                    // 32768 us

    k_prep   <<<PREP_MLW, 256, 0, stream>>>(x, shr, pw, ew0, ew1, ew2, mw1, mw2,
                                            gw, fgw, fe0, pooled, projb, w0b, w1b, w2pb, dummy);
    k_route  <<<8,        256, 0, stream>>>(fe0, pooled, mw1, mb1, mw2, mb2, gw, fgw, gates, gsum);
    k_experts<<<8 * NT,   256, 0, stream>>>(x, shr, w0b, w1b, w2pb, projb, gates, gsum, out);
}